// Round 9
// baseline (257.735 us; speedup 1.0000x reference)
//
#include <hip/hip_runtime.h>

#define B_ 4
#define C_ 256
#define D_ 128
#define N_ 4096
#define BN_ 16384   // B_*N_

typedef unsigned short u16t;
typedef _Float16 f16t;
typedef f16t f16x8 __attribute__((ext_vector_type(8)));
typedef f16t f16x4 __attribute__((ext_vector_type(4)));
typedef float f32x4 __attribute__((ext_vector_type(4)));

static __device__ __forceinline__ u16t f2h(float f) {
  f16t h = (f16t)f; u16t u; __builtin_memcpy(&u, &h, 2); return u;
}
static __device__ __forceinline__ float h2f(u16t u) {
  f16t h; __builtin_memcpy(&h, &u, 2); return (float)h;
}

// ---------------- weight prep: cast fp32 weights to fp16, concat theta/phi ----------------
__global__ __launch_bounds__(256) void prep_w(const float* __restrict__ th_w,
                                              const float* __restrict__ ph_w,
                                              const float* __restrict__ th_b,
                                              const float* __restrict__ ph_b,
                                              const float* __restrict__ g_w,
                                              const float* __restrict__ w_w,
                                              u16t* __restrict__ Wc, u16t* __restrict__ gwc,
                                              u16t* __restrict__ wwc, float* __restrict__ bc) {
  const int idx = blockIdx.x * 256 + threadIdx.x;
  if (idx < 65536) {
    const int j = idx >> 8, c = idx & 255;
    const float v = (j < 128) ? th_w[j * 256 + c] : ph_w[(j - 128) * 256 + c];
    Wc[idx] = f2h(v);
  } else if (idx < 98304) {
    const int i = idx - 65536;
    gwc[i] = f2h(g_w[i]);
  } else if (idx < 131072) {
    const int i = idx - 98304;
    wwc[i] = f2h(w_w[i]);
  } else if (idx < 131328) {
    const int j = idx - 131072;
    bc[j] = (j < 128) ? th_b[j] : ph_b[j - 128];
  }
}

// ---------------- transpose + cast: x fp32 [B][C][N] -> xT fp16 [B][N][C] ----------------
__global__ __launch_bounds__(256) void transpose_x(const float* __restrict__ x,
                                                   u16t* __restrict__ xT) {
  __shared__ u16t t[32][33];
  const int b = blockIdx.z, c0 = blockIdx.y * 32, n0 = blockIdx.x * 32;
  const int tid = threadIdx.x;
  {
    const int cl = tid >> 3, n4 = (tid & 7) * 4;
    const float4 v = *(const float4*)(x + ((size_t)b * C_ + c0 + cl) * N_ + n0 + n4);
    t[n4 + 0][cl] = f2h(v.x);
    t[n4 + 1][cl] = f2h(v.y);
    t[n4 + 2][cl] = f2h(v.z);
    t[n4 + 3][cl] = f2h(v.w);
  }
  __syncthreads();
  {
    const int nl = tid >> 3, c4 = (tid & 7) * 4;
    unsigned int lo = (unsigned int)t[nl][c4 + 0] | ((unsigned int)t[nl][c4 + 1] << 16);
    unsigned int hi = (unsigned int)t[nl][c4 + 2] | ((unsigned int)t[nl][c4 + 3] << 16);
    uint2 o; o.x = lo; o.y = hi;
    *(uint2*)(xT + ((size_t)b * N_ + n0 + nl) * C_ + c0 + c4) = o;
  }
}

// ---------------- GEMM, 64x64 tile / BK=64: C[m][j] = sum_k A[m][k]*B[j][k] --------------
// 4 waves in 2x2, each wave 32x32 (acc 2x2). LDS 18.4 KB -> 4-8 blocks/CU for latency hiding.
template<int COLBIAS, int STATS>
__global__ __launch_bounds__(256)
void gemm64(const u16t* __restrict__ Ab, long long aBS,
            const u16t* __restrict__ Bb, long long bBS,
            u16t* __restrict__ Cb, long long cBS, int ldc,
            const float* __restrict__ bias, float* __restrict__ stats, int K) {
  __shared__ __attribute__((aligned(16))) u16t lA[64 * 72];
  __shared__ __attribute__((aligned(16))) u16t lB[64 * 72];
  const int z = blockIdx.z;
  const u16t* A = Ab + (size_t)z * aBS;
  const u16t* B = Bb + (size_t)z * bBS;
  const int m0 = blockIdx.y * 64, j0 = blockIdx.x * 64;
  const int tid = threadIdx.x, lane = tid & 63, wave = tid >> 6;
  const int quad = lane >> 4, l16 = lane & 15;
  const int wm = wave & 1, wj = wave >> 1;
  const int srow = tid >> 3, ssg = tid & 7;

  const f32x4 zero = {0.f, 0.f, 0.f, 0.f};
  f32x4 acc[2][2];
#pragma unroll
  for (int mi = 0; mi < 2; ++mi)
#pragma unroll
    for (int ji = 0; ji < 2; ++ji) acc[mi][ji] = zero;

  for (int k0 = 0; k0 < K; k0 += 64) {
#pragma unroll
    for (int c = 0; c < 2; ++c) {
      const int row = c * 32 + srow;
      *(uint4*)&lA[row * 72 + ssg * 8] = *(const uint4*)(A + (size_t)(m0 + row) * K + k0 + ssg * 8);
      *(uint4*)&lB[row * 72 + ssg * 8] = *(const uint4*)(B + (size_t)(j0 + row) * K + k0 + ssg * 8);
    }
    __syncthreads();
#pragma unroll
    for (int kc = 0; kc < 2; ++kc) {
      f16x8 af[2], bf[2];
#pragma unroll
      for (int i = 0; i < 2; ++i)
        af[i] = *(const f16x8*)&lA[(wm * 32 + i * 16 + l16) * 72 + kc * 32 + quad * 8];
#pragma unroll
      for (int i = 0; i < 2; ++i)
        bf[i] = *(const f16x8*)&lB[(wj * 32 + i * 16 + l16) * 72 + kc * 32 + quad * 8];
#pragma unroll
      for (int mi = 0; mi < 2; ++mi)
#pragma unroll
        for (int ji = 0; ji < 2; ++ji)
          acc[mi][ji] = __builtin_amdgcn_mfma_f32_16x16x32_f16(af[mi], bf[ji], acc[mi][ji], 0, 0, 0);
    }
    __syncthreads();
  }

  float cb[2];
  if (COLBIAS) {
#pragma unroll
    for (int ji = 0; ji < 2; ++ji) cb[ji] = bias[j0 + wj * 32 + ji * 16 + l16];
  }
#pragma unroll
  for (int mi = 0; mi < 2; ++mi) {
#pragma unroll
    for (int r = 0; r < 4; ++r) {
      const int row = m0 + wm * 32 + mi * 16 + quad * 4 + r;
      const float rb = COLBIAS ? 0.f : bias[row];
      float s1 = 0.f, s2 = 0.f;
#pragma unroll
      for (int ji = 0; ji < 2; ++ji) {
        const int col = j0 + wj * 32 + ji * 16 + l16;
        float v = acc[mi][ji][r] + (COLBIAS ? cb[ji] : rb);
        Cb[(size_t)z * cBS + (size_t)row * ldc + col] = f2h(v);
        s1 += v; s2 += v * v;
      }
      if (STATS) {
        s1 += __shfl_xor(s1, 1); s1 += __shfl_xor(s1, 2);
        s1 += __shfl_xor(s1, 4); s1 += __shfl_xor(s1, 8);
        s2 += __shfl_xor(s2, 1); s2 += __shfl_xor(s2, 2);
        s2 += __shfl_xor(s2, 4); s2 += __shfl_xor(s2, 8);
        if (l16 == 0) {
          atomicAdd(&stats[row], s1);
          atomicAdd(&stats[256 + row], s2);
        }
      }
    }
  }
}

// ---------------- flash attention, S^T formulation, kv-split x4 (unchanged r8) ----------
__global__ __launch_bounds__(256)
void attn(const u16t* __restrict__ QK, const u16t* __restrict__ V,
          u16t* __restrict__ On0, u16t* __restrict__ On1, float* __restrict__ ml) {
  const int b = blockIdx.y;
  const int split = blockIdx.z;
  const int n0 = blockIdx.x * 64;
  const int kv0 = split * (N_ / 4);
  const int tid = threadIdx.x, lane = tid & 63, wave = tid >> 6;
  const int quad = lane >> 4, l16 = lane & 15;
  __shared__ __attribute__((aligned(16))) u16t Qs[64 * 136];
  __shared__ __attribute__((aligned(16))) u16t Ks[64 * 136];
  __shared__ __attribute__((aligned(16))) u16t Vs[128 * 72];
  const u16t* QKb = QK + (size_t)b * N_ * 256;
  const u16t* Vb  = V  + (size_t)b * D_ * N_;

#pragma unroll
  for (int rr = 0; rr < 4; ++rr) {
    const int ch = rr * 256 + tid;
    const int row = ch >> 4, sg = ch & 15;
    *(uint4*)&Qs[row * 136 + sg * 8] = *(const uint4*)(QKb + (size_t)(n0 + row) * 256 + sg * 8);
  }

  const f32x4 zero = {0.f, 0.f, 0.f, 0.f};
  f32x4 o[8];
#pragma unroll
  for (int db = 0; db < 8; ++db) o[db] = zero;
  float m = -1e30f, l = 0.f;

  for (int kv = kv0; kv < kv0 + N_ / 4; kv += 64) {
#pragma unroll
    for (int rr = 0; rr < 4; ++rr) {
      const int ch = rr * 256 + tid;
      const int row = ch >> 4, sg = ch & 15;
      *(uint4*)&Ks[row * 136 + sg * 8] =
          *(const uint4*)(QKb + (size_t)(kv + row) * 256 + 128 + sg * 8);
    }
#pragma unroll
    for (int rr = 0; rr < 4; ++rr) {
      const int ch = rr * 256 + tid;
      const int row = ch >> 3, sg = ch & 7;
      *(uint4*)&Vs[row * 72 + sg * 8] = *(const uint4*)(Vb + (size_t)row * N_ + kv + sg * 8);
    }
    __syncthreads();

    f32x4 s[4];
#pragma unroll
    for (int ci = 0; ci < 4; ++ci) s[ci] = zero;
#pragma unroll
    for (int kc = 0; kc < 4; ++kc) {
      f16x8 qf = *(const f16x8*)&Qs[(wave * 16 + l16) * 136 + (kc * 4 + quad) * 8];
#pragma unroll
      for (int ci = 0; ci < 4; ++ci) {
        f16x8 kf = *(const f16x8*)&Ks[(ci * 16 + l16) * 136 + (kc * 4 + quad) * 8];
        s[ci] = __builtin_amdgcn_mfma_f32_16x16x32_f16(kf, qf, s[ci], 0, 0, 0);
      }
    }

    float mx = s[0][0];
#pragma unroll
    for (int ci = 0; ci < 4; ++ci)
#pragma unroll
      for (int r = 0; r < 4; ++r) mx = fmaxf(mx, s[ci][r]);
    mx = fmaxf(mx, __shfl_xor(mx, 16));
    mx = fmaxf(mx, __shfl_xor(mx, 32));
    const float mnew = fmaxf(m, mx);
    const float al = __expf(m - mnew);
    float psum = 0.f;
    f16x4 pb[4];
#pragma unroll
    for (int ci = 0; ci < 4; ++ci) {
#pragma unroll
      for (int r = 0; r < 4; ++r) {
        const float p = __expf(s[ci][r] - mnew);
        psum += p;
        pb[ci][r] = (f16t)p;
      }
    }
    psum += __shfl_xor(psum, 16);
    psum += __shfl_xor(psum, 32);
    l = l * al + psum;
    m = mnew;

#pragma unroll
    for (int db = 0; db < 8; ++db) {
#pragma unroll
      for (int r = 0; r < 4; ++r) o[db][r] *= al;
    }
#pragma unroll
    for (int ci = 0; ci < 4; ++ci) {
#pragma unroll
      for (int db = 0; db < 8; ++db) {
        f16x4 av = *(const f16x4*)&Vs[(db * 16 + l16) * 72 + ci * 16 + quad * 4];
        o[db] = __builtin_amdgcn_mfma_f32_16x16x16f16(av, pb[ci], o[db], 0, 0, 0);
      }
    }
    __syncthreads();
  }

  const int q = n0 + wave * 16 + l16;
  u16t* Onb = (split < 2) ? On0 : On1;
  const int sp = split & 1;
  const float inv = 1.0f / l;
  u16t* yrow = Onb + (((size_t)sp * B_ + b) * N_ + q) * D_;
#pragma unroll
  for (int db = 0; db < 8; ++db) {
    f16x4 pk;
#pragma unroll
    for (int r = 0; r < 4; ++r) pk[r] = (f16t)(o[db][r] * inv);
    *(f16x4*)(yrow + db * 16 + quad * 4) = pk;
  }
  if (quad == 0) {
    float* mlp = ml + ((size_t)split * BN_ + (size_t)b * N_ + q) * 2;
    mlp[0] = m; mlp[1] = l;
  }
}

// ---------------- combine the 4 kv-splits (in-place over split 0) ----------------
__global__ __launch_bounds__(256) void attn_combine(u16t* __restrict__ O0,
                                                    const u16t* __restrict__ O2,
                                                    const float* __restrict__ ml) {
  const int idx = blockIdx.x * 256 + threadIdx.x;
  const int row = idx >> 4, cg = idx & 15;
  float mv[4], lv[4];
  float mstar = -1e30f;
#pragma unroll
  for (int s = 0; s < 4; ++s) {
    mv[s] = ml[((size_t)s * BN_ + row) * 2];
    lv[s] = ml[((size_t)s * BN_ + row) * 2 + 1];
    mstar = fmaxf(mstar, mv[s]);
  }
  float w[4], wsum = 0.f;
#pragma unroll
  for (int s = 0; s < 4; ++s) { w[s] = __expf(mv[s] - mstar) * lv[s]; wsum += w[s]; }
  const float inv = 1.0f / wsum;
#pragma unroll
  for (int s = 0; s < 4; ++s) w[s] *= inv;

  const size_t off = (size_t)row * D_ + cg * 8;
  const size_t half = (size_t)BN_ * D_;
  uint4 a0 = *(const uint4*)(O0 + off);
  uint4 a1 = *(const uint4*)(O0 + half + off);
  uint4 a2 = *(const uint4*)(O2 + off);
  uint4 a3 = *(const uint4*)(O2 + half + off);
  uint4 y;
  const unsigned* p0 = &a0.x; const unsigned* p1 = &a1.x;
  const unsigned* p2 = &a2.x; const unsigned* p3 = &a3.x;
  unsigned* py = &y.x;
#pragma unroll
  for (int i = 0; i < 4; ++i) {
    const float lo = w[0] * h2f((u16t)(p0[i] & 0xffff)) + w[1] * h2f((u16t)(p1[i] & 0xffff)) +
                     w[2] * h2f((u16t)(p2[i] & 0xffff)) + w[3] * h2f((u16t)(p3[i] & 0xffff));
    const float hi = w[0] * h2f((u16t)(p0[i] >> 16)) + w[1] * h2f((u16t)(p1[i] >> 16)) +
                     w[2] * h2f((u16t)(p2[i] >> 16)) + w[3] * h2f((u16t)(p3[i] >> 16));
    py[i] = (unsigned)f2h(lo) | ((unsigned)f2h(hi) << 16);
  }
  *(uint4*)(O0 + off) = y;
}

// ---------------- BN finalize + residual (fp32 in/out) ----------------
__global__ __launch_bounds__(256) void bn_fin(const u16t* __restrict__ wy,
                                              const float* __restrict__ x,
                                              const float* __restrict__ stats,
                                              const float* __restrict__ gamma,
                                              const float* __restrict__ beta,
                                              float* __restrict__ out) {
  const int b = blockIdx.z, c = blockIdx.y;
  const int n = blockIdx.x * 256 + threadIdx.x;
  const size_t off = ((size_t)b * C_ + c) * N_ + n;
  const float inv_n = 1.0f / 16384.0f;
  const float mean = stats[c] * inv_n;
  const float var = stats[256 + c] * inv_n - mean * mean;
  const float rs = rsqrtf(var + 1e-5f);
  const float g = gamma[c], bt = beta[c];
  out[off] = (h2f(wy[off]) - mean) * rs * g + bt + x[off];
}

// ---------------- launch ----------------
extern "C" void kernel_launch(void* const* d_in, const int* in_sizes, int n_in,
                              void* d_out, int out_size, void* d_ws, size_t ws_size,
                              hipStream_t stream) {
  const float* x     = (const float*)d_in[0];
  const float* g_w   = (const float*)d_in[1];
  const float* g_b   = (const float*)d_in[2];
  const float* th_w  = (const float*)d_in[3];
  const float* th_b  = (const float*)d_in[4];
  const float* ph_w  = (const float*)d_in[5];
  const float* ph_b  = (const float*)d_in[6];
  const float* w_w   = (const float*)d_in[7];
  const float* w_b   = (const float*)d_in[8];
  const float* gamma = (const float*)d_in[9];
  const float* beta  = (const float*)d_in[10];
  float* out = (float*)d_out;
  char* ws = (char*)d_ws;

  u16t* xT  = (u16t*)(ws);
  u16t* Y   = (u16t*)(ws);                  // combine output, in-place over split0
  u16t* QK  = (u16t*)(ws + 8388608);
  u16t* wy  = (u16t*)(ws + 8388608);        // overlays QK (QK dead after attn)
  u16t* V   = (u16t*)(ws + 16777216);
  u16t* Wc  = (u16t*)(ws + 20971520);
  u16t* gwc = (u16t*)(ws + 21102592);
  u16t* wwc = (u16t*)(ws + 21168128);
  float* bc = (float*)(ws + 21233664);
  float* stats = (float*)(ws + 21234688);
  float* ml = (float*)(ws + 21236736);

  hipMemsetAsync(stats, 0, 2048, stream);

  prep_w<<<dim3(513), dim3(256), 0, stream>>>(th_w, ph_w, th_b, ph_b, g_w, w_w,
                                              Wc, gwc, wwc, bc);
  transpose_x<<<dim3(128, 8, B_), dim3(256), 0, stream>>>(x, xT);

  // QK projection: [B*N,256] = xT[B*N,256c] @ Wc[256j,256c]^T + bc (col bias); batch folded
  gemm64<1, 0><<<dim3(4, 256, 1), dim3(256), 0, stream>>>(
      xT, 0LL, Wc, 0LL, QK, 0LL, 256, bc, (float*)nullptr, C_);
  // V projection: [B,128d,N] = gwc[128d,256c] @ xT[B,N,256c]^T + g_b (row bias)
  gemm64<0, 0><<<dim3(64, 2, B_), dim3(256), 0, stream>>>(
      gwc, 0LL, xT, (long long)N_ * C_, V, (long long)D_ * N_, N_,
      g_b, (float*)nullptr, C_);

  attn<<<dim3(64, B_, 4), dim3(256), 0, stream>>>(QK, V, (u16t*)ws, (u16t*)d_out, ml);
  attn_combine<<<dim3(1024), dim3(256), 0, stream>>>((u16t*)ws, (u16t*)d_out, ml);

  // w_y: [B,256c,N] = wwc[256c,128d] @ Y[B,N,128d]^T + w_b (fp16 out + fp32 BN stats)
  gemm64<0, 1><<<dim3(64, 4, B_), dim3(256), 0, stream>>>(
      wwc, 0LL, Y, (long long)N_ * D_, wy, (long long)C_ * N_, N_,
      w_b, stats, D_);

  bn_fin<<<dim3(16, 256, B_), dim3(256), 0, stream>>>(wy, x, stats, gamma, beta, out);
}

// Round 10
// 233.626 us; speedup vs baseline: 1.1032x; 1.1032x over previous
//
#include <hip/hip_runtime.h>

#define B_ 4
#define C_ 256
#define D_ 128
#define N_ 4096
#define BN_ 16384   // B_*N_

typedef unsigned short u16t;
typedef _Float16 f16t;
typedef f16t f16x8 __attribute__((ext_vector_type(8)));
typedef f16t f16x4 __attribute__((ext_vector_type(4)));
typedef float f32x4 __attribute__((ext_vector_type(4)));

static __device__ __forceinline__ u16t f2h(float f) {
  f16t h = (f16t)f; u16t u; __builtin_memcpy(&u, &h, 2); return u;
}
static __device__ __forceinline__ float h2f(u16t u) {
  f16t h; __builtin_memcpy(&h, &u, 2); return (float)h;
}

// ---------------- weight prep: cast fp32 weights to fp16, concat theta/phi ----------------
__global__ __launch_bounds__(256) void prep_w(const float* __restrict__ th_w,
                                              const float* __restrict__ ph_w,
                                              const float* __restrict__ th_b,
                                              const float* __restrict__ ph_b,
                                              const float* __restrict__ g_w,
                                              const float* __restrict__ w_w,
                                              u16t* __restrict__ Wc, u16t* __restrict__ gwc,
                                              u16t* __restrict__ wwc, float* __restrict__ bc) {
  const int idx = blockIdx.x * 256 + threadIdx.x;
  if (idx < 65536) {
    const int j = idx >> 8, c = idx & 255;
    const float v = (j < 128) ? th_w[j * 256 + c] : ph_w[(j - 128) * 256 + c];
    Wc[idx] = f2h(v);
  } else if (idx < 98304) {
    const int i = idx - 65536;
    gwc[i] = f2h(g_w[i]);
  } else if (idx < 131072) {
    const int i = idx - 98304;
    wwc[i] = f2h(w_w[i]);
  } else if (idx < 131328) {
    const int j = idx - 131072;
    bc[j] = (j < 128) ? th_b[j] : ph_b[j - 128];
  }
}

// ---------------- transpose + cast: x fp32 [B][C][N] -> xT fp16 [B][N][C] ----------------
__global__ __launch_bounds__(256) void transpose_x(const float* __restrict__ x,
                                                   u16t* __restrict__ xT) {
  __shared__ u16t t[32][33];
  const int b = blockIdx.z, c0 = blockIdx.y * 32, n0 = blockIdx.x * 32;
  const int tid = threadIdx.x;
  {
    const int cl = tid >> 3, n4 = (tid & 7) * 4;
    const float4 v = *(const float4*)(x + ((size_t)b * C_ + c0 + cl) * N_ + n0 + n4);
    t[n4 + 0][cl] = f2h(v.x);
    t[n4 + 1][cl] = f2h(v.y);
    t[n4 + 2][cl] = f2h(v.z);
    t[n4 + 3][cl] = f2h(v.w);
  }
  __syncthreads();
  {
    const int nl = tid >> 3, c4 = (tid & 7) * 4;
    unsigned int lo = (unsigned int)t[nl][c4 + 0] | ((unsigned int)t[nl][c4 + 1] << 16);
    unsigned int hi = (unsigned int)t[nl][c4 + 2] | ((unsigned int)t[nl][c4 + 3] << 16);
    uint2 o; o.x = lo; o.y = hi;
    *(uint2*)(xT + ((size_t)b * N_ + n0 + nl) * C_ + c0 + c4) = o;
  }
}

// ---------------- GEMM (round-8 form, 128x128 tile): C[m][j] = sum_k A[m][k]*B[j][k] -----
template<int COLBIAS, int STATS>
__global__ __launch_bounds__(256)
void gemm_bt(const u16t* __restrict__ Ab, long long aBS,
             const u16t* __restrict__ Bb, long long bBS,
             u16t* __restrict__ Cb, long long cBS, int ldc,
             const float* __restrict__ bias, float* __restrict__ stats, int K) {
  __shared__ __attribute__((aligned(16))) u16t lA[128 * 40];
  __shared__ __attribute__((aligned(16))) u16t lB[128 * 40];
  const int z = blockIdx.z;
  const u16t* A = Ab + (size_t)z * aBS;
  const u16t* B = Bb + (size_t)z * bBS;
  const int m0 = blockIdx.y * 128, j0 = blockIdx.x * 128;
  const int tid = threadIdx.x, lane = tid & 63, wave = tid >> 6;
  const int quad = lane >> 4, l16 = lane & 15;
  const int wm = wave & 1, wj = wave >> 1;

  const f32x4 zero = {0.f, 0.f, 0.f, 0.f};
  f32x4 acc[4][4];
#pragma unroll
  for (int mi = 0; mi < 4; ++mi)
#pragma unroll
    for (int ji = 0; ji < 4; ++ji) acc[mi][ji] = zero;

  for (int k0 = 0; k0 < K; k0 += 32) {
#pragma unroll
    for (int rr = 0; rr < 2; ++rr) {
      const int idx = rr * 256 + tid;
      const int row = idx >> 2, sg = idx & 3;
      *(uint4*)&lA[row * 40 + sg * 8] = *(const uint4*)(A + (size_t)(m0 + row) * K + k0 + sg * 8);
      *(uint4*)&lB[row * 40 + sg * 8] = *(const uint4*)(B + (size_t)(j0 + row) * K + k0 + sg * 8);
    }
    __syncthreads();
    f16x8 af[4], bfr[4];
#pragma unroll
    for (int i = 0; i < 4; ++i)
      af[i] = *(const f16x8*)&lA[(wm * 64 + i * 16 + l16) * 40 + quad * 8];
#pragma unroll
    for (int i = 0; i < 4; ++i)
      bfr[i] = *(const f16x8*)&lB[(wj * 64 + i * 16 + l16) * 40 + quad * 8];
#pragma unroll
    for (int mi = 0; mi < 4; ++mi)
#pragma unroll
      for (int ji = 0; ji < 4; ++ji)
        acc[mi][ji] = __builtin_amdgcn_mfma_f32_16x16x32_f16(af[mi], bfr[ji], acc[mi][ji], 0, 0, 0);
    __syncthreads();
  }

  float cb[4];
  if (COLBIAS) {
#pragma unroll
    for (int ji = 0; ji < 4; ++ji) cb[ji] = bias[j0 + wj * 64 + ji * 16 + l16];
  }
#pragma unroll
  for (int mi = 0; mi < 4; ++mi) {
#pragma unroll
    for (int r = 0; r < 4; ++r) {
      const int row = m0 + wm * 64 + mi * 16 + quad * 4 + r;
      const float rb = COLBIAS ? 0.f : bias[row];
      float s1 = 0.f, s2 = 0.f;
#pragma unroll
      for (int ji = 0; ji < 4; ++ji) {
        const int col = j0 + wj * 64 + ji * 16 + l16;
        float v = acc[mi][ji][r] + (COLBIAS ? cb[ji] : rb);
        Cb[(size_t)z * cBS + (size_t)row * ldc + col] = f2h(v);
        s1 += v; s2 += v * v;
      }
      if (STATS) {
        s1 += __shfl_xor(s1, 1); s1 += __shfl_xor(s1, 2);
        s1 += __shfl_xor(s1, 4); s1 += __shfl_xor(s1, 8);
        s2 += __shfl_xor(s2, 1); s2 += __shfl_xor(s2, 2);
        s2 += __shfl_xor(s2, 4); s2 += __shfl_xor(s2, 8);
        if (l16 == 0) {
          atomicAdd(&stats[row], s1);
          atomicAdd(&stats[256 + row], s2);
        }
      }
    }
  }
}

// ---------------- flash attention, S^T formulation, kv-split x4, REGISTER Q ----------------
// Q fragment is lane-private in the S^T formulation (B-operand: Q[q=wave*16+l16][c]),
// so it loads global->VGPR once (no Qs LDS). LDS = Ks+Vs = 35,840 B -> 4 blocks/CU.
__global__ __launch_bounds__(256, 4)
void attn(const u16t* __restrict__ QK, const u16t* __restrict__ V,
          u16t* __restrict__ On0, u16t* __restrict__ On1, float* __restrict__ ml) {
  const int b = blockIdx.y;
  const int split = blockIdx.z;
  const int n0 = blockIdx.x * 64;
  const int kv0 = split * (N_ / 4);
  const int tid = threadIdx.x, lane = tid & 63, wave = tid >> 6;
  const int quad = lane >> 4, l16 = lane & 15;
  __shared__ __attribute__((aligned(16))) u16t Ks[64 * 136];
  __shared__ __attribute__((aligned(16))) u16t Vs[128 * 72];
  const u16t* QKb = QK + (size_t)b * N_ * 256;
  const u16t* Vb  = V  + (size_t)b * D_ * N_;

  // Q once, straight to registers (this lane's q-row, all 128 channels)
  f16x8 qf[4];
  {
    const u16t* qrow = QKb + (size_t)(n0 + wave * 16 + l16) * 256;
#pragma unroll
    for (int kc = 0; kc < 4; ++kc)
      qf[kc] = *(const f16x8*)(qrow + kc * 32 + quad * 8);
  }

  const f32x4 zero = {0.f, 0.f, 0.f, 0.f};
  f32x4 o[8];
#pragma unroll
  for (int db = 0; db < 8; ++db) o[db] = zero;
  float m = -1e30f, l = 0.f;

  for (int kv = kv0; kv < kv0 + N_ / 4; kv += 64) {
#pragma unroll
    for (int rr = 0; rr < 4; ++rr) {
      const int ch = rr * 256 + tid;
      const int row = ch >> 4, sg = ch & 15;
      *(uint4*)&Ks[row * 136 + sg * 8] =
          *(const uint4*)(QKb + (size_t)(kv + row) * 256 + 128 + sg * 8);
    }
#pragma unroll
    for (int rr = 0; rr < 4; ++rr) {
      const int ch = rr * 256 + tid;
      const int row = ch >> 3, sg = ch & 7;
      *(uint4*)&Vs[row * 72 + sg * 8] = *(const uint4*)(Vb + (size_t)row * N_ + kv + sg * 8);
    }
    __syncthreads();

    // S^T = K Q^T : acc[ci] covers kv-block ci (rows), this wave's 16 q (cols)
    f32x4 s[4];
#pragma unroll
    for (int ci = 0; ci < 4; ++ci) s[ci] = zero;
#pragma unroll
    for (int kc = 0; kc < 4; ++kc) {
#pragma unroll
      for (int ci = 0; ci < 4; ++ci) {
        f16x8 kf = *(const f16x8*)&Ks[(ci * 16 + l16) * 136 + (kc * 4 + quad) * 8];
        s[ci] = __builtin_amdgcn_mfma_f32_16x16x32_f16(kf, qf[kc], s[ci], 0, 0, 0);
      }
    }

    // wave-local online softmax over this lane's q-column (16 kv values in-lane)
    float mx = s[0][0];
#pragma unroll
    for (int ci = 0; ci < 4; ++ci)
#pragma unroll
      for (int r = 0; r < 4; ++r) mx = fmaxf(mx, s[ci][r]);
    mx = fmaxf(mx, __shfl_xor(mx, 16));
    mx = fmaxf(mx, __shfl_xor(mx, 32));
    const float mnew = fmaxf(m, mx);
    const float al = __expf(m - mnew);
    float psum = 0.f;
    f16x4 pb[4];
#pragma unroll
    for (int ci = 0; ci < 4; ++ci) {
#pragma unroll
      for (int r = 0; r < 4; ++r) {
        const float p = __expf(s[ci][r] - mnew);
        psum += p;
        pb[ci][r] = (f16t)p;
      }
    }
    psum += __shfl_xor(psum, 16);
    psum += __shfl_xor(psum, 32);
    l = l * al + psum;
    m = mnew;

    // rescale O^T and accumulate O^T += V^T P^T (register-resident)
#pragma unroll
    for (int db = 0; db < 8; ++db) {
#pragma unroll
      for (int r = 0; r < 4; ++r) o[db][r] *= al;
    }
#pragma unroll
    for (int ci = 0; ci < 4; ++ci) {
#pragma unroll
      for (int db = 0; db < 8; ++db) {
        f16x4 av = *(const f16x4*)&Vs[(db * 16 + l16) * 72 + ci * 16 + quad * 4];
        o[db] = __builtin_amdgcn_mfma_f32_16x16x16f16(av, pb[ci], o[db], 0, 0, 0);
      }
    }
    __syncthreads();
  }

  // epilogue: normalize by own l, store O^T (lane's q = wave*16+l16, d = db*16+quad*4+r)
  const int q = n0 + wave * 16 + l16;
  u16t* Onb = (split < 2) ? On0 : On1;
  const int sp = split & 1;
  const float inv = 1.0f / l;
  u16t* yrow = Onb + (((size_t)sp * B_ + b) * N_ + q) * D_;
#pragma unroll
  for (int db = 0; db < 8; ++db) {
    f16x4 pk;
#pragma unroll
    for (int r = 0; r < 4; ++r) pk[r] = (f16t)(o[db][r] * inv);
    *(f16x4*)(yrow + db * 16 + quad * 4) = pk;
  }
  if (quad == 0) {
    float* mlp = ml + ((size_t)split * BN_ + (size_t)b * N_ + q) * 2;
    mlp[0] = m; mlp[1] = l;
  }
}

// ---------------- combine the 4 kv-splits (in-place over split 0) ----------------
__global__ __launch_bounds__(256) void attn_combine(u16t* __restrict__ O0,
                                                    const u16t* __restrict__ O2,
                                                    const float* __restrict__ ml) {
  const int idx = blockIdx.x * 256 + threadIdx.x;
  const int row = idx >> 4, cg = idx & 15;
  float mv[4], lv[4];
  float mstar = -1e30f;
#pragma unroll
  for (int s = 0; s < 4; ++s) {
    mv[s] = ml[((size_t)s * BN_ + row) * 2];
    lv[s] = ml[((size_t)s * BN_ + row) * 2 + 1];
    mstar = fmaxf(mstar, mv[s]);
  }
  float w[4], wsum = 0.f;
#pragma unroll
  for (int s = 0; s < 4; ++s) { w[s] = __expf(mv[s] - mstar) * lv[s]; wsum += w[s]; }
  const float inv = 1.0f / wsum;
#pragma unroll
  for (int s = 0; s < 4; ++s) w[s] *= inv;

  const size_t off = (size_t)row * D_ + cg * 8;
  const size_t half = (size_t)BN_ * D_;
  uint4 a0 = *(const uint4*)(O0 + off);
  uint4 a1 = *(const uint4*)(O0 + half + off);
  uint4 a2 = *(const uint4*)(O2 + off);
  uint4 a3 = *(const uint4*)(O2 + half + off);
  uint4 y;
  const unsigned* p0 = &a0.x; const unsigned* p1 = &a1.x;
  const unsigned* p2 = &a2.x; const unsigned* p3 = &a3.x;
  unsigned* py = &y.x;
#pragma unroll
  for (int i = 0; i < 4; ++i) {
    const float lo = w[0] * h2f((u16t)(p0[i] & 0xffff)) + w[1] * h2f((u16t)(p1[i] & 0xffff)) +
                     w[2] * h2f((u16t)(p2[i] & 0xffff)) + w[3] * h2f((u16t)(p3[i] & 0xffff));
    const float hi = w[0] * h2f((u16t)(p0[i] >> 16)) + w[1] * h2f((u16t)(p1[i] >> 16)) +
                     w[2] * h2f((u16t)(p2[i] >> 16)) + w[3] * h2f((u16t)(p3[i] >> 16));
    py[i] = (unsigned)f2h(lo) | ((unsigned)f2h(hi) << 16);
  }
  *(uint4*)(O0 + off) = y;
}

// ---------------- BN finalize + residual (fp32 in/out) ----------------
__global__ __launch_bounds__(256) void bn_fin(const u16t* __restrict__ wy,
                                              const float* __restrict__ x,
                                              const float* __restrict__ stats,
                                              const float* __restrict__ gamma,
                                              const float* __restrict__ beta,
                                              float* __restrict__ out) {
  const int b = blockIdx.z, c = blockIdx.y;
  const int n = blockIdx.x * 256 + threadIdx.x;
  const size_t off = ((size_t)b * C_ + c) * N_ + n;
  const float inv_n = 1.0f / 16384.0f;
  const float mean = stats[c] * inv_n;
  const float var = stats[256 + c] * inv_n - mean * mean;
  const float rs = rsqrtf(var + 1e-5f);
  const float g = gamma[c], bt = beta[c];
  out[off] = (h2f(wy[off]) - mean) * rs * g + bt + x[off];
}

// ---------------- launch ----------------
extern "C" void kernel_launch(void* const* d_in, const int* in_sizes, int n_in,
                              void* d_out, int out_size, void* d_ws, size_t ws_size,
                              hipStream_t stream) {
  const float* x     = (const float*)d_in[0];
  const float* g_w   = (const float*)d_in[1];
  const float* g_b   = (const float*)d_in[2];
  const float* th_w  = (const float*)d_in[3];
  const float* th_b  = (const float*)d_in[4];
  const float* ph_w  = (const float*)d_in[5];
  const float* ph_b  = (const float*)d_in[6];
  const float* w_w   = (const float*)d_in[7];
  const float* w_b   = (const float*)d_in[8];
  const float* gamma = (const float*)d_in[9];
  const float* beta  = (const float*)d_in[10];
  float* out = (float*)d_out;
  char* ws = (char*)d_ws;

  u16t* xT  = (u16t*)(ws);
  u16t* Y   = (u16t*)(ws);                  // combine output, in-place over split0
  u16t* QK  = (u16t*)(ws + 8388608);
  u16t* wy  = (u16t*)(ws + 8388608);        // overlays QK (QK dead after attn)
  u16t* V   = (u16t*)(ws + 16777216);
  u16t* Wc  = (u16t*)(ws + 20971520);
  u16t* gwc = (u16t*)(ws + 21102592);
  u16t* wwc = (u16t*)(ws + 21168128);
  float* bc = (float*)(ws + 21233664);
  float* stats = (float*)(ws + 21234688);
  float* ml = (float*)(ws + 21236736);

  hipMemsetAsync(stats, 0, 2048, stream);

  prep_w<<<dim3(513), dim3(256), 0, stream>>>(th_w, ph_w, th_b, ph_b, g_w, w_w,
                                              Wc, gwc, wwc, bc);
  transpose_x<<<dim3(128, 8, B_), dim3(256), 0, stream>>>(x, xT);

  // QK projection: [B,N,256] = xT[B,N,256c] @ Wc[256j,256c]^T + bc (col bias)
  gemm_bt<1, 0><<<dim3(2, 32, B_), dim3(256), 0, stream>>>(
      xT, (long long)N_ * C_, Wc, 0LL, QK, (long long)N_ * 256, 256,
      bc, (float*)nullptr, C_);
  // V projection: [B,128d,N] = gwc[128d,256c] @ xT[B,N,256c]^T + g_b (row bias)
  gemm_bt<0, 0><<<dim3(32, 1, B_), dim3(256), 0, stream>>>(
      gwc, 0LL, xT, (long long)N_ * C_, V, (long long)D_ * N_, N_,
      g_b, (float*)nullptr, C_);

  attn<<<dim3(64, B_, 4), dim3(256), 0, stream>>>(QK, V, (u16t*)ws, (u16t*)d_out, ml);
  attn_combine<<<dim3(1024), dim3(256), 0, stream>>>((u16t*)ws, (u16t*)d_out, ml);

  // w_y: [B,256c,N] = wwc[256c,128d] @ Y[B,N,128d]^T + w_b (fp16 out + fp32 BN stats)
  gemm_bt<0, 1><<<dim3(32, 2, B_), dim3(256), 0, stream>>>(
      wwc, 0LL, Y, (long long)N_ * D_, wy, (long long)C_ * N_, N_,
      w_b, stats, D_);

  bn_fin<<<dim3(16, 256, B_), dim3(256), 0, stream>>>(wy, x, stats, gamma, beta, out);
}